// Round 3
// baseline (788.836 us; speedup 1.0000x reference)
//
#include <hip/hip_runtime.h>

typedef unsigned short u16;
typedef unsigned int u32;
typedef __bf16 bf16x8 __attribute__((ext_vector_type(8)));
typedef float f32x16 __attribute__((ext_vector_type(16)));

// Problem constants: B=4, N=2048, C=2048, H=16, DH=128
// tokens BN = 8192, qkv row = 3*C = 6144

__device__ __forceinline__ u16 f2bf(float f) {
    u32 u = __builtin_bit_cast(u32, f);
    u += 0x7FFFu + ((u >> 16) & 1u);   // round-to-nearest-even
    return (u16)(u >> 16);
}
__device__ __forceinline__ float bf2f(u16 h) {
    return __builtin_bit_cast(float, ((u32)h) << 16);
}

// ---------------- fp32 -> bf16 conversion (vectorized) ----------------
__global__ __launch_bounds__(256) void cvt_bf16(const float* __restrict__ in,
                                                u16* __restrict__ out, int n4) {
    int i = blockIdx.x * 256 + threadIdx.x;
    if (i >= n4) return;
    const float4 f = reinterpret_cast<const float4*>(in)[i];
    ushort4 o;
    o.x = f2bf(f.x); o.y = f2bf(f.y); o.z = f2bf(f.z); o.w = f2bf(f.w);
    reinterpret_cast<ushort4*>(out)[i] = o;
}

// ---------------- async global->LDS copy, 16 B per lane ----------------
typedef const __attribute__((address_space(1))) void* gas1_t;
typedef __attribute__((address_space(3))) void* las3_t;
__device__ __forceinline__ void cp16(const void* g, void* l) {
    __builtin_amdgcn_global_load_lds((gas1_t)g, (las3_t)l, 16, 0, 0);
}

#define BAR()        __builtin_amdgcn_s_barrier()
#define SBAR0()      __builtin_amdgcn_sched_barrier(0)
#define WAIT_VM(n)   asm volatile("s_waitcnt vmcnt(" #n ")" ::: "memory")

// ==================== 128x128 ring-4 pipelined bf16 NT GEMM ====================
// C = A(MxK) * B(NxK)^T + bias.  BM=BN=128, BK=32, 256 threads = 4 waves (2x2),
// wave tile 64x64 = 2x2 of 32x32x16 MFMA, acc = 4 x f32x16 = 64 regs.
//
// This is the round-0 structure (proven 793 TF) with its two measured costs
// removed:
//  (1) the per-K-tile vmcnt(0)+__syncthreads drain (~540 cyc/K-tile exposed
//      HBM latency) -> ring-4 LDS (stage tile t+3 while computing t) with
//      counted WAIT_VM(8): at each barrier we wait only for tile t+1, which
//      was issued 2 full K-tiles (~1300 cyc) earlier > ~900 cyc HBM latency.
//      vm ledger (4 cp16/tile/thread): prologue t0,t1,t2 = 12 out -> vm(8)
//      drains t0. steady: stage t+3 -> 12 out; vm(8) drains t+1; leaves
//      t+2,t+3 in flight. Never 0 in the loop.
//  (2) 2.5e7 LDS bank-conflict cycles -> k-chunk-major layout (proven 0
//      conflicts in round 1): per matrix per buf, granule(kc 0..3, r 0..127)
//      of 16 B at kc*2048 + r*16.  gload_lds dest is linear (tid*16); the
//      permutation is in the per-lane GLOBAL source (m173).  Frag reads:
//      each 32-lane half reads one contiguous 512 B run -> conflict-free.
// Safety: reads of tile t complete before the barrier because MFMA issue
// requires operands (compiler's counted lgkmcnt); stage of t+3 only
// overwrites tile t-1's buffer, whose last reads finished before the
// previous barrier.  Raw s_barrier + "memory"-clobber waits + sched_barrier
// fences replace __syncthreads (which would re-introduce the vmcnt(0) drain).
// XCD swizzle (bijective, nwg%8==0): XCD x computes a contiguous run of
// flat ids -> same A-panel rows stay in one XCD's L2.

template <int OUT_BF16>
__global__ __launch_bounds__(256, 2) void gemm_nt(const u16* __restrict__ A,
                                                  const u16* __restrict__ Bm,
                                                  const float* __restrict__ bias,
                                                  void* __restrict__ Cout,
                                                  int M, int N, int K) {
    // ring-4: buf*16384 + [A: 0 | B: 8192] + kc*2048 + r*16
    __shared__ __align__(16) char lds[4 * 16384];

    const int tid  = threadIdx.x;
    const int lane = tid & 63;
    const int wave = tid >> 6;
    const int wm   = (wave >> 1) * 64;  // wave row offset in tile
    const int wn   = (wave & 1) * 64;   // wave col offset in tile
    const int r32  = lane & 31;
    const int half = lane >> 5;         // 0..1

    // bijective XCD swizzle on the flat block id (nwg % 8 == 0 at our grids)
    const int gx   = gridDim.x;
    const int flat = blockIdx.y * gx + blockIdx.x;
    const int q8   = (gx * gridDim.y) >> 3;
    const int swz  = (flat & 7) * q8 + (flat >> 3);
    const long bm  = (long)(swz / gx) * 128;
    const long bn  = (long)(swz % gx) * 128;

    // staging: thread t owns granules t and t+256 of each 128x32 tile:
    // (r = t&127, kc = t>>7 and t>>7 + 2).  LDS dest linear = tid*16 (+4096).
    const int sr  = tid & 127;
    const int skc = tid >> 7;           // 0..1
    const u16* gA = A  + (bm + sr) * (long)K + skc * 8;
    const u16* gB = Bm + (bn + sr) * (long)K + skc * 8;
    char* ld0 = lds + tid * 16;

#define STAGE(BUF, KT)                                              \
    { const long ko = (long)(KT) * 32;                              \
      char* d = ld0 + (BUF) * 16384;                                \
      cp16(gA + ko, d);      cp16(gA + ko + 16, d + 4096);          \
      cp16(gB + ko, d + 8192); cp16(gB + ko + 16, d + 12288); }

    // frag read bases: A frag(mt,ks) lane byte =
    //   buf*16384 + (2*ks + half)*2048 + (wm + mt*32 + r32)*16
    const char* pA = lds + half * 2048 + (wm + r32) * 16;
    const char* pB = lds + 8192 + half * 2048 + (wn + r32) * 16;

    f32x16 acc[2][2];
#pragma unroll
    for (int i = 0; i < 2; ++i)
#pragma unroll
        for (int j = 0; j < 2; ++j)
#pragma unroll
            for (int r = 0; r < 16; ++r) acc[i][j][r] = 0.f;

    const int NT = K >> 5;              // 64 K-tiles at K=2048

    // prologue: stage tiles 0,1,2 into bufs 0,1,2; drain tile 0 only
    STAGE(0, 0); STAGE(1, 1); STAGE(2, 2);
    WAIT_VM(8);
    BAR(); SBAR0();

#pragma unroll 4
    for (int t = 0; t < NT; ++t) {
        int kt = t + 3; if (kt >= NT) kt -= NT;   // tail wrap: harmless refetch
        STAGE((t + 3) & 3, kt);

        const int bo = (t & 3) * 16384;
        bf16x8 a[2][2], b[2][2];
#pragma unroll
        for (int ks = 0; ks < 2; ++ks)
#pragma unroll
            for (int u = 0; u < 2; ++u) {
                a[u][ks] = *(const bf16x8*)(pA + bo + ks * 4096 + u * 512);
                b[u][ks] = *(const bf16x8*)(pB + bo + ks * 4096 + u * 512);
            }

        __builtin_amdgcn_s_setprio(1);
#pragma unroll
        for (int ks = 0; ks < 2; ++ks)
#pragma unroll
            for (int i = 0; i < 2; ++i)
#pragma unroll
                for (int j = 0; j < 2; ++j)
                    acc[i][j] = __builtin_amdgcn_mfma_f32_32x32x16_bf16(
                        a[i][ks], b[j][ks], acc[i][j], 0, 0, 0);
        __builtin_amdgcn_s_setprio(0);

        // counted drain: tile t+1 (issued 2 K-tiles ago) now complete;
        // leave t+2, t+3 (8 insts) in flight.  Then release the buffers.
        WAIT_VM(8);
        BAR(); SBAR0();
    }
#undef STAGE

    WAIT_VM(0);   // drain wasted tail prefetches before epilogue vmem

    // epilogue: 32x32 C/D layout: col = lane&31, row = (reg&3) + 8*(reg>>2) + 4*half
#pragma unroll
    for (int j = 0; j < 2; ++j) {
        const long col = bn + wn + j * 32 + r32;
        const float bc = bias[col];
#pragma unroll
        for (int i = 0; i < 2; ++i) {
#pragma unroll
            for (int reg = 0; reg < 16; ++reg) {
                const long row = bm + wm + i * 32 + (reg & 3) + 8 * (reg >> 2) + 4 * half;
                float v = acc[i][j][reg] + bc;
                if (OUT_BF16)
                    ((u16*)Cout)[row * (long)N + col] = f2bf(v);
                else
                    ((float*)Cout)[row * (long)N + col] = v;
            }
        }
    }
}

// ---------------- per-token head-mixing attention ----------------
// One block (256 thr) per token. q,k,v: 16x128 each from qkv row (3*2048 bf16).
// S = q k^T / sqrt(2048) (16x16), softmax rows, O = S v (16x128).
// Write O to scrambled layout: row h*128 + n/16, col (n%16)*128 + d (bf16).
__global__ __launch_bounds__(256) void attn(const u16* __restrict__ qkv,
                                            u16* __restrict__ outb) {
    __shared__ float sQ[16 * 132];   // +4 pad: stride 132 floats kills bank conflicts
    __shared__ float sK[16 * 132];
    __shared__ float sV[16 * 132];
    __shared__ float sP[16 * 17];

    const int tid = threadIdx.x;
    const int token = blockIdx.x;
    const int b = token >> 11;      // /2048
    const int n = token & 2047;
    const u16* row = qkv + (long)token * 6144;

    // ---- load q,k,v -> LDS as fp32 (each thread: 8 contiguous elems) ----
    {
        const int r  = tid >> 4;          // 0..15
        const int c8 = (tid & 15) * 8;    // 0,8,...,120
#pragma unroll
        for (int m = 0; m < 3; ++m) {
            const uint4 u = *reinterpret_cast<const uint4*>(row + m * 2048 + tid * 8);
            float* dst = (m == 0 ? sQ : (m == 1 ? sK : sV)) + r * 132 + c8;
            float4 lo, hi;
            lo.x = bf2f((u16)u.x); lo.y = bf2f((u16)(u.x >> 16));
            lo.z = bf2f((u16)u.y); lo.w = bf2f((u16)(u.y >> 16));
            hi.x = bf2f((u16)u.z); hi.y = bf2f((u16)(u.z >> 16));
            hi.z = bf2f((u16)u.w); hi.w = bf2f((u16)(u.w >> 16));
            *reinterpret_cast<float4*>(dst)     = lo;
            *reinterpret_cast<float4*>(dst + 4) = hi;
        }
    }
    __syncthreads();

    // ---- S + softmax: thread (h,g) = (tid>>4, tid&15); 16-lane-group reductions ----
    {
        const int h = tid >> 4, g = tid & 15;
        const float4* qr = reinterpret_cast<const float4*>(&sQ[h * 132]);
        const float4* kr = reinterpret_cast<const float4*>(&sK[g * 132]);
        float s = 0.f;
#pragma unroll
        for (int d = 0; d < 32; ++d) {
            const float4 a = qr[d], k4 = kr[d];
            s += a.x * k4.x + a.y * k4.y + a.z * k4.z + a.w * k4.w;
        }
        s *= 0.022097086912079608f;   // 1/sqrt(2048)
        float mx = s;
#pragma unroll
        for (int o = 8; o >= 1; o >>= 1) mx = fmaxf(mx, __shfl_xor(mx, o, 16));
        const float e = __expf(s - mx);
        float sum = e;
#pragma unroll
        for (int o = 8; o >= 1; o >>= 1) sum += __shfl_xor(sum, o, 16);
        sP[h * 17 + g] = e / sum;
    }
    __syncthreads();

    // ---- O = P @ V; thread (h, dblk) handles d = dblk*8 .. +7 ----
    {
        const int h = tid >> 4, dblk = tid & 15;
        float p[16];
#pragma unroll
        for (int g = 0; g < 16; ++g) p[g] = sP[h * 17 + g];
        float4 o0 = {0.f, 0.f, 0.f, 0.f}, o1 = {0.f, 0.f, 0.f, 0.f};
#pragma unroll
        for (int g = 0; g < 16; ++g) {
            const float* vr = &sV[g * 132 + dblk * 8];
            const float4 v0 = *reinterpret_cast<const float4*>(vr);
            const float4 v1 = *reinterpret_cast<const float4*>(vr + 4);
            o0.x += p[g] * v0.x; o0.y += p[g] * v0.y; o0.z += p[g] * v0.z; o0.w += p[g] * v0.w;
            o1.x += p[g] * v1.x; o1.y += p[g] * v1.y; o1.z += p[g] * v1.z; o1.w += p[g] * v1.w;
        }
        // scrambled reshape target: row = h*128 + n/16, col = (n%16)*128 + d
        const long rr = (long)h * 128 + (n >> 4);
        const long cc = (long)(n & 15) * 128 + dblk * 8;
        u16* dst = outb + ((long)b * 2048 + rr) * 2048 + cc;
        uint4 pk;
        pk.x = (u32)f2bf(o0.x) | ((u32)f2bf(o0.y) << 16);
        pk.y = (u32)f2bf(o0.z) | ((u32)f2bf(o0.w) << 16);
        pk.z = (u32)f2bf(o1.x) | ((u32)f2bf(o1.y) << 16);
        pk.w = (u32)f2bf(o1.z) | ((u32)f2bf(o1.w) << 16);
        *reinterpret_cast<uint4*>(dst) = pk;
    }
}

// ---------------- launch ----------------
extern "C" void kernel_launch(void* const* d_in, const int* in_sizes, int n_in,
                              void* d_out, int out_size, void* d_ws, size_t ws_size,
                              hipStream_t stream) {
    const float* x     = (const float*)d_in[0];   // (4,2048,2048)
    const float* w_qkv = (const float*)d_in[1];   // (6144,2048)
    const float* b_qkv = (const float*)d_in[2];   // (6144,)
    const float* w_out = (const float*)d_in[3];   // (2048,2048)
    const float* b_out = (const float*)d_in[4];   // (2048,)
    float* out = (float*)d_out;                   // (4,2048,2048) fp32

    char* ws = (char*)d_ws;
    // workspace layout (bytes):
    //   xb    @ 0          : 8192*2048*2  = 33554432
    //   wqkvb @ 33554432   : 6144*2048*2  = 25165824
    //   woutb @ 58720256   : 2048*2048*2  =  8388608
    //   qkvb  @ 67108864   : 8192*6144*2  = 100663296   (end 167772160)
    //   attnb aliases xb (x no longer needed after GEMM1)
    u16* xb    = (u16*)(ws);
    u16* wqkvb = (u16*)(ws + 33554432);
    u16* woutb = (u16*)(ws + 58720256);
    u16* qkvb  = (u16*)(ws + 67108864);
    u16* attnb = xb;

    cvt_bf16<<<16384, 256, 0, stream>>>(x,     xb,    16777216 / 4);
    cvt_bf16<<<12288, 256, 0, stream>>>(w_qkv, wqkvb, 12582912 / 4);
    cvt_bf16<<<4096,  256, 0, stream>>>(w_out, woutb, 4194304 / 4);

    dim3 g1(48, 64);  // N/128, M/128
    gemm_nt<1><<<g1, 256, 0, stream>>>(xb, wqkvb, b_qkv, qkvb, 8192, 6144, 2048);

    attn<<<8192, 256, 0, stream>>>(qkvb, attnb);

    dim3 g2(16, 64);  // N/128, M/128
    gemm_nt<0><<<g2, 256, 0, stream>>>(attnb, woutb, b_out, out, 8192, 2048, 2048);
}

// Round 4
// 470.829 us; speedup vs baseline: 1.6754x; 1.6754x over previous
//
#include <hip/hip_runtime.h>

typedef unsigned short u16;
typedef unsigned int u32;
typedef __bf16 bf16x8 __attribute__((ext_vector_type(8)));
typedef float f32x16 __attribute__((ext_vector_type(16)));

// Problem constants: B=4, N=2048, C=2048, H=16, DH=128
// tokens BN = 8192, qkv row = 3*C = 6144

__device__ __forceinline__ u16 f2bf(float f) {
    u32 u = __builtin_bit_cast(u32, f);
    u += 0x7FFFu + ((u >> 16) & 1u);   // round-to-nearest-even
    return (u16)(u >> 16);
}
__device__ __forceinline__ float bf2f(u16 h) {
    return __builtin_bit_cast(float, ((u32)h) << 16);
}

// ---------------- fp32 -> bf16 conversion (vectorized) ----------------
__global__ __launch_bounds__(256) void cvt_bf16(const float* __restrict__ in,
                                                u16* __restrict__ out, int n4) {
    int i = blockIdx.x * 256 + threadIdx.x;
    if (i >= n4) return;
    const float4 f = reinterpret_cast<const float4*>(in)[i];
    ushort4 o;
    o.x = f2bf(f.x); o.y = f2bf(f.y); o.z = f2bf(f.z); o.w = f2bf(f.w);
    reinterpret_cast<ushort4*>(out)[i] = o;
}

// ---------------- async global->LDS copy, 16 B per lane ----------------
typedef const __attribute__((address_space(1))) void* gas1_t;
typedef __attribute__((address_space(3))) void* las3_t;
__device__ __forceinline__ void cp16(const void* g, void* l) {
    __builtin_amdgcn_global_load_lds((gas1_t)g, (las3_t)l, 16, 0, 0);
}

#define BAR()        __builtin_amdgcn_s_barrier()
#define WAIT_LGKM0() asm volatile("s_waitcnt lgkmcnt(0)" ::: "memory")
#define WAIT_VM6()   asm volatile("s_waitcnt vmcnt(6)" ::: "memory")
#define WAIT_VM0()   asm volatile("s_waitcnt vmcnt(0)" ::: "memory")

// ==================== 256x256 8-phase bf16 NT GEMM (line-local swizzle) ====
// C = A(MxK) * B(NxK)^T + bias.  BM=BN=256, BK=64, 512 threads = 8 waves
// (2M x 4N), per-wave output 128x64 = 4x2 of 32x32x16 MFMA, acc = 8 x f32x16.
//
// LDS 128 KiB: A in [0,64K): buf*32768 + half*16384; B at +65536.
// Half-tile (128 rows x 64 cols bf16 = 16 KiB) granule map (16 B granules):
//   granule(r, kc) at slot  r*8 + ((kc + r) & 7)          (LINE-LOCAL swizzle)
// - Staging (linear LDS dest tid*16): thread t sources (row = t>>3,
//   kc = ((t&7) - (t>>3)) & 7) -> each 8-thread group covers one row's full
//   128 B = whole cache lines.  COALESCED (round-3's row-per-lane scatter
//   caused the 4x FETCH blowup; this kills it).
// - Frag reads (32x32x16: lane(r32,half), frag(mt,ks): kc = 2*ks+half,
//   r = mt*32+r32): slot%8 = (2*ks + half + r32) & 7 -> each 16-lane quarter
//   hits every 4-bank group exactly twice = conflict-free (same distribution
//   that measured 0 conflicts in rounds 1-3).
//
// Phase/stage/vmcnt schedule = round-1's (numerically verified twice):
// per K-tile: 4 phases = C-quadrants (Mhalf x Nhalf) over full BK=64:
//   ph1: read a(mt0-1,ks0-3) + b0(ks0-3); STAGE next A-h1 | Q(0,0)
//   ph2: read b1(ks0-3)                                   | Q(0,1)
//   ph3: read a(mt2-3,ks0-3); STAGE B-h0,B-h1 (tile T+2)  | Q(1,0)
//   ph4: STAGE A-h0 (tile T+2)                            | Q(1,1); vm(6)
// each phase: {reads; stage} BAR; lgkm(0); setprio(1); 8 MFMA; setprio(0); BAR
// vm ledger (2 cp16/STAGE, 8 cp16/K-tile): at ph4-end outstanding=14, vm(6)
// drains 8 = the NEXT tile's buffer complete before its phases read it.
// Never drains to 0 in the loop.  Tail prefetch wraps mod NT (harmless).

__device__ __forceinline__ void ld_a2(bf16x8 (&a)[2][4], const char* base,
                                      const int (&o)[4], int mt0) {
#pragma unroll
    for (int m = 0; m < 2; ++m)
#pragma unroll
        for (int ks = 0; ks < 4; ++ks)
            a[m][ks] = *(const bf16x8*)(base + (mt0 + m) * 4096 + o[ks]);
}
__device__ __forceinline__ void ld_b4(bf16x8 (&bb)[4], const char* base,
                                      const int (&o)[4], int nt) {
#pragma unroll
    for (int ks = 0; ks < 4; ++ks)
        bb[ks] = *(const bf16x8*)(base + nt * 4096 + o[ks]);
}

template <int MH, int NH>
__device__ __forceinline__ void quad(f32x16 (&acc)[4][2], bf16x8 (&a)[2][4],
                                     bf16x8 (&b)[2][4]) {
    __builtin_amdgcn_s_setprio(1);
#pragma unroll
    for (int ks = 0; ks < 4; ++ks)
#pragma unroll
        for (int m = 0; m < 2; ++m)
            acc[MH * 2 + m][NH] = __builtin_amdgcn_mfma_f32_32x32x16_bf16(
                a[m][ks], b[NH][ks], acc[MH * 2 + m][NH], 0, 0, 0);
    __builtin_amdgcn_s_setprio(0);
}

template <int OUT_BF16>
__global__ __launch_bounds__(512, 2) void gemm_nt(const u16* __restrict__ A,
                                                  const u16* __restrict__ Bm,
                                                  const float* __restrict__ bias,
                                                  void* __restrict__ Cout,
                                                  int M, int N, int K) {
    __shared__ __align__(16) char lds[131072];

    const int tid  = threadIdx.x;
    const int lane = tid & 63;
    const int wave = tid >> 6;
    const int wm   = wave >> 2;     // 0..1  (M half)
    const int wn   = wave & 3;      // 0..3  (N quarter)
    const int r32  = lane & 31;
    const int half = lane >> 5;     // 0..1

    const long bm = (long)blockIdx.y * 256;
    const long bn = (long)blockIdx.x * 256;

    // ---- staging sources (line-local): thread t -> granules t and t+512 ----
    const int srow = tid >> 3;                       // 0..63
    const int skc  = ((tid & 7) - srow) & 7;         // permuted within the row
    const u16* gA0 = A  + (bm + srow) * (long)K + skc * 8;
    const u16* gA1 = gA0 + 128 * (long)K;
    const u16* gB0 = Bm + (bn + srow) * (long)K + skc * 8;
    const u16* gB1 = gB0 + 128 * (long)K;
    const long hK  = 64 * (long)K;                   // +64 rows (granule +512)
    char* ldst = lds + tid * 16;

#define STAGE_A(HALF, BUF, KT)                                    \
    { const u16* g = ((HALF) ? gA1 : gA0) + (KT) * 64;            \
      char* d = ldst + (BUF) * 32768 + (HALF) * 16384;            \
      cp16(g, d); cp16(g + hK, d + 8192); }
#define STAGE_B(HALF, BUF, KT)                                    \
    { const u16* g = ((HALF) ? gB1 : gB0) + (KT) * 64;            \
      char* d = ldst + 65536 + (BUF) * 32768 + (HALF) * 16384;    \
      cp16(g, d); cp16(g + hK, d + 8192); }

    // ---- frag read bases + per-lane swizzle offsets ----
    const char* rdA = lds + wm * 16384 + r32 * 128;
    const char* rdB = lds + 65536 + (wn >> 1) * 16384 + ((wn & 1) * 64 + r32) * 128;
    const int c = (half + r32) & 7;
    int o[4];
#pragma unroll
    for (int ks = 0; ks < 4; ++ks) o[ks] = ((c + 2 * ks) & 7) << 4;

    f32x16 acc[4][2];
#pragma unroll
    for (int i = 0; i < 4; ++i)
#pragma unroll
        for (int j = 0; j < 2; ++j)
#pragma unroll
            for (int r = 0; r < 16; ++r) acc[i][j][r] = 0.f;

    const int NT = K >> 6;          // 32 K-tiles at K=2048

    // ---- prologue: tile0 full (buf0) + tile1 {B0,B1,A0} (buf1) ----
    STAGE_B(0, 0, 0); STAGE_B(1, 0, 0); STAGE_A(0, 0, 0); STAGE_A(1, 0, 0);
    STAGE_B(0, 1, 1); STAGE_B(1, 1, 1); STAGE_A(0, 1, 1);
    WAIT_VM6();
    BAR();

    bf16x8 a[2][4], b[2][4];

#define KTILE(RB, A1B, A1K, BB, BKT, A0B, A0K)                    \
    {                                                             \
        const char* rA = rdA + (RB) * 32768;                      \
        const char* rB = rdB + (RB) * 32768;                      \
        /* ph1: Q(0,0) */                                         \
        ld_a2(a, rA, o, 0);                                       \
        ld_b4(b[0], rB, o, 0);                                    \
        STAGE_A(1, A1B, A1K);                                     \
        BAR(); WAIT_LGKM0();                                      \
        quad<0, 0>(acc, a, b);                                    \
        BAR();                                                    \
        /* ph2: Q(0,1) */                                         \
        ld_b4(b[1], rB, o, 1);                                    \
        BAR(); WAIT_LGKM0();                                      \
        quad<0, 1>(acc, a, b);                                    \
        BAR();                                                    \
        /* ph3: Q(1,0) */                                         \
        ld_a2(a, rA, o, 2);                                       \
        STAGE_B(0, BB, BKT); STAGE_B(1, BB, BKT);                 \
        BAR(); WAIT_LGKM0();                                      \
        quad<1, 0>(acc, a, b);                                    \
        BAR();                                                    \
        /* ph4: Q(1,1) */                                         \
        STAGE_A(0, A0B, A0K);                                     \
        BAR(); WAIT_LGKM0();                                      \
        quad<1, 1>(acc, a, b);                                    \
        WAIT_VM6();                                               \
        BAR();                                                    \
    }

    const int NIT = NT >> 1;
    for (int it = 0; it < NIT; ++it) {
        const int T = 2 * it;
        int t2 = T + 2; if (t2 >= NT) t2 -= NT;
        int t3 = T + 3; if (t3 >= NT) t3 -= NT;
        KTILE(0, /*A1->*/1, T + 1, /*B->*/0, t2, /*A0->*/0, t2);
        KTILE(1, /*A1->*/0, t2,    /*B->*/1, t3, /*A0->*/1, t3);
    }
#undef KTILE
#undef STAGE_A
#undef STAGE_B

    WAIT_VM0();   // drain wasted tail prefetches before epilogue vmem

    // ---- epilogue: 32x32 C/D layout col=lane&31, row=(reg&3)+8*(reg>>2)+4*half
    // stores: 32 cols x 2 B = full 64 B lines (round-0 proven) ----
    const long crow0 = bm + wm * 128;
    const long ccol0 = bn + wn * 64;
#pragma unroll
    for (int nt = 0; nt < 2; ++nt) {
        const long col = ccol0 + nt * 32 + r32;
        const float bc = bias[col];
#pragma unroll
        for (int mt = 0; mt < 4; ++mt) {
#pragma unroll
            for (int reg = 0; reg < 16; ++reg) {
                const long row = crow0 + mt * 32 + (reg & 3) + 8 * (reg >> 2) + 4 * half;
                float v = acc[mt][nt][reg] + bc;
                if (OUT_BF16)
                    ((u16*)Cout)[row * (long)N + col] = f2bf(v);
                else
                    ((float*)Cout)[row * (long)N + col] = v;
            }
        }
    }
}

// ---------------- per-token head-mixing attention ----------------
// One block (256 thr) per token. q,k,v: 16x128 each from qkv row (3*2048 bf16).
// S = q k^T / sqrt(2048) (16x16), softmax rows, O = S v (16x128).
// Write O to scrambled layout: row h*128 + n/16, col (n%16)*128 + d (bf16).
__global__ __launch_bounds__(256) void attn(const u16* __restrict__ qkv,
                                            u16* __restrict__ outb) {
    __shared__ float sQ[16 * 132];   // +4 pad: stride 132 floats kills bank conflicts
    __shared__ float sK[16 * 132];
    __shared__ float sV[16 * 132];
    __shared__ float sP[16 * 17];

    const int tid = threadIdx.x;
    const int token = blockIdx.x;
    const int b = token >> 11;      // /2048
    const int n = token & 2047;
    const u16* row = qkv + (long)token * 6144;

    // ---- load q,k,v -> LDS as fp32 (each thread: 8 contiguous elems) ----
    {
        const int r  = tid >> 4;          // 0..15
        const int c8 = (tid & 15) * 8;    // 0,8,...,120
#pragma unroll
        for (int m = 0; m < 3; ++m) {
            const uint4 u = *reinterpret_cast<const uint4*>(row + m * 2048 + tid * 8);
            float* dst = (m == 0 ? sQ : (m == 1 ? sK : sV)) + r * 132 + c8;
            float4 lo, hi;
            lo.x = bf2f((u16)u.x); lo.y = bf2f((u16)(u.x >> 16));
            lo.z = bf2f((u16)u.y); lo.w = bf2f((u16)(u.y >> 16));
            hi.x = bf2f((u16)u.z); hi.y = bf2f((u16)(u.z >> 16));
            hi.z = bf2f((u16)u.w); hi.w = bf2f((u16)(u.w >> 16));
            *reinterpret_cast<float4*>(dst)     = lo;
            *reinterpret_cast<float4*>(dst + 4) = hi;
        }
    }
    __syncthreads();

    // ---- S + softmax: thread (h,g) = (tid>>4, tid&15); 16-lane-group reductions ----
    {
        const int h = tid >> 4, g = tid & 15;
        const float4* qr = reinterpret_cast<const float4*>(&sQ[h * 132]);
        const float4* kr = reinterpret_cast<const float4*>(&sK[g * 132]);
        float s = 0.f;
#pragma unroll
        for (int d = 0; d < 32; ++d) {
            const float4 a = qr[d], k4 = kr[d];
            s += a.x * k4.x + a.y * k4.y + a.z * k4.z + a.w * k4.w;
        }
        s *= 0.022097086912079608f;   // 1/sqrt(2048)
        float mx = s;
#pragma unroll
        for (int o = 8; o >= 1; o >>= 1) mx = fmaxf(mx, __shfl_xor(mx, o, 16));
        const float e = __expf(s - mx);
        float sum = e;
#pragma unroll
        for (int o = 8; o >= 1; o >>= 1) sum += __shfl_xor(sum, o, 16);
        sP[h * 17 + g] = e / sum;
    }
    __syncthreads();

    // ---- O = P @ V; thread (h, dblk) handles d = dblk*8 .. +7 ----
    {
        const int h = tid >> 4, dblk = tid & 15;
        float p[16];
#pragma unroll
        for (int g = 0; g < 16; ++g) p[g] = sP[h * 17 + g];
        float4 o0 = {0.f, 0.f, 0.f, 0.f}, o1 = {0.f, 0.f, 0.f, 0.f};
#pragma unroll
        for (int g = 0; g < 16; ++g) {
            const float* vr = &sV[g * 132 + dblk * 8];
            const float4 v0 = *reinterpret_cast<const float4*>(vr);
            const float4 v1 = *reinterpret_cast<const float4*>(vr + 4);
            o0.x += p[g] * v0.x; o0.y += p[g] * v0.y; o0.z += p[g] * v0.z; o0.w += p[g] * v0.w;
            o1.x += p[g] * v1.x; o1.y += p[g] * v1.y; o1.z += p[g] * v1.z; o1.w += p[g] * v1.w;
        }
        // scrambled reshape target: row = h*128 + n/16, col = (n%16)*128 + d
        const long rr = (long)h * 128 + (n >> 4);
        const long cc = (long)(n & 15) * 128 + dblk * 8;
        u16* dst = outb + ((long)b * 2048 + rr) * 2048 + cc;
        uint4 pk;
        pk.x = (u32)f2bf(o0.x) | ((u32)f2bf(o0.y) << 16);
        pk.y = (u32)f2bf(o0.z) | ((u32)f2bf(o0.w) << 16);
        pk.z = (u32)f2bf(o1.x) | ((u32)f2bf(o1.y) << 16);
        pk.w = (u32)f2bf(o1.z) | ((u32)f2bf(o1.w) << 16);
        *reinterpret_cast<uint4*>(dst) = pk;
    }
}

// ---------------- launch ----------------
extern "C" void kernel_launch(void* const* d_in, const int* in_sizes, int n_in,
                              void* d_out, int out_size, void* d_ws, size_t ws_size,
                              hipStream_t stream) {
    const float* x     = (const float*)d_in[0];   // (4,2048,2048)
    const float* w_qkv = (const float*)d_in[1];   // (6144,2048)
    const float* b_qkv = (const float*)d_in[2];   // (6144,)
    const float* w_out = (const float*)d_in[3];   // (2048,2048)
    const float* b_out = (const float*)d_in[4];   // (2048,)
    float* out = (float*)d_out;                   // (4,2048,2048) fp32

    char* ws = (char*)d_ws;
    // workspace layout (bytes):
    //   xb    @ 0          : 8192*2048*2  = 33554432
    //   wqkvb @ 33554432   : 6144*2048*2  = 25165824
    //   woutb @ 58720256   : 2048*2048*2  =  8388608
    //   qkvb  @ 67108864   : 8192*6144*2  = 100663296   (end 167772160)
    //   attnb aliases xb (x no longer needed after GEMM1)
    u16* xb    = (u16*)(ws);
    u16* wqkvb = (u16*)(ws + 33554432);
    u16* woutb = (u16*)(ws + 58720256);
    u16* qkvb  = (u16*)(ws + 67108864);
    u16* attnb = xb;

    cvt_bf16<<<16384, 256, 0, stream>>>(x,     xb,    16777216 / 4);
    cvt_bf16<<<12288, 256, 0, stream>>>(w_qkv, wqkvb, 12582912 / 4);
    cvt_bf16<<<4096,  256, 0, stream>>>(w_out, woutb, 4194304 / 4);

    dim3 g1(24, 32);  // N/256, M/256
    gemm_nt<1><<<g1, 512, 0, stream>>>(xb, wqkvb, b_qkv, qkvb, 8192, 6144, 2048);

    attn<<<8192, 256, 0, stream>>>(qkvb, attnb);

    dim3 g2(8, 32);   // N/256, M/256
    gemm_nt<0><<<g2, 512, 0, stream>>>(attnb, woutb, b_out, out, 8192, 2048, 2048);
}